// Round 8
// baseline (143.637 us; speedup 1.0000x reference)
//
#include <hip/hip_runtime.h>
#include <cstdint>

#define N_EMB 6272      // B*W*H = 8*28*28
#define DIMD  128
#define M_BANK 16384
#define BATCH 8
#define PPB   784       // patches per batch
#define KNN   9
#define EPSF  1e-12f

typedef unsigned long long u64;
typedef _Float16 f16x8 __attribute__((ext_vector_type(8)));
typedef float    f32x4 __attribute__((ext_vector_type(4)));

static __device__ __forceinline__ u64 umin64(u64 a, u64 b) { return b < a ? b : a; }
static __device__ __forceinline__ u64 umax64(u64 a, u64 b) { return b > a ? b : a; }

// async global->LDS, 16B per lane, linear LDS dest (wave-uniform base + lane*16)
static __device__ __forceinline__ void gll16(const _Float16* g, _Float16* l) {
    __builtin_amdgcn_global_load_lds(
        (__attribute__((address_space(1))) void*)(const void*)g,
        (__attribute__((address_space(3))) void*)l, 16, 0, 0);
}

// ---------------- Phase A: convert f32 -> fp16 (pre-swizzled) + exact norms --
// Also initializes packed[] (replaces a separate memset dispatch).
__global__ __launch_bounds__(256) void convert_kernel(
        const float* __restrict__ emb, const float* __restrict__ bank,
        _Float16* __restrict__ GAh, _Float16* __restrict__ GBh,
        float* __restrict__ x2, float* __restrict__ y2,
        u64* __restrict__ packed) {
    const int gid = blockIdx.x * 256 + threadIdx.x;
    if (gid < N_EMB) packed[gid] = ~0ull;
    const int row = gid >> 4;
    const int chunk = gid & 15;
    const float* src;
    _Float16* dh;
    float* nrm;
    int R;
    if (row < M_BANK) {
        src = bank + (size_t)row * DIMD; dh = GBh; nrm = y2; R = row;
    } else {
        R = row - M_BANK;
        src = emb + (size_t)R * DIMD; dh = GAh; nrm = x2;
    }
    float4 v0 = ((const float4*)src)[chunk * 2];
    float4 v1 = ((const float4*)src)[chunk * 2 + 1];
    float f[8] = {v0.x, v0.y, v0.z, v0.w, v1.x, v1.y, v1.z, v1.w};
    f16x8 h;
    float s = 0.f;
    #pragma unroll
    for (int e = 0; e < 8; ++e) {
        h[e] = (_Float16)f[e];
        s += f[e] * f[e];
    }
    const int q = chunk >> 2, jj = chunk & 3;
    const int jj2 = jj ^ ((R >> 1) & 3);
    *(f16x8*)(dh + (size_t)R * DIMD + q * 32 + jj2 * 8) = h;
    #pragma unroll
    for (int off = 1; off < 16; off <<= 1) s += __shfl_xor(s, off, 16);
    if (chunk == 0) nrm[R] = s;
}

// ---------------- Phase B: MFMA approx dist^2 + per-row min/argmin ----------
// A-frags loaded DIRECTLY global->regs (L2/L3-resident, swizzle in address);
// LDS = 32KB B double-buffer only. No launch_bounds min-wave cap: natural
// VGPR use ~150-165 -> 3 waves/SIMD, matches 784-block grid (3.06/CU).
// Fold: biased (+512) value, 5 low mantissa bits -> (t*4+j) tag, u32 min.

static __device__ __forceinline__ void stageB(
        const _Float16* __restrict__ GBh, _Float16* dst,
        int mrow0, int h, int srow, int se8) {
    #pragma unroll
    for (int j = 0; j < 2; ++j) {
        const int row = srow + j * 64;
        #pragma unroll
        for (int q = 0; q < 2; ++q)
            gll16(GBh + (size_t)(mrow0 + row) * DIMD + h * 64 + q * 32 + se8,
                  dst + q * 4096 + row * 32 + se8);
    }
}

template<int H, bool FIRST>
static __device__ __forceinline__ void computeB(
        const _Float16* bb, const f16x8 (&a)[4][4], f32x4 (&acc)[4][4],
        int wm, int g, int r16) {
    f16x8 b[4][2];
    #pragma unroll
    for (int fj = 0; fj < 4; ++fj) {
        const int row = wm * 64 + fj * 16 + r16;
        const int sw = (g ^ ((row >> 1) & 3)) << 3;
        b[fj][0] = *(const f16x8*)&bb[row * 32 + sw];
        b[fj][1] = *(const f16x8*)&bb[4096 + row * 32 + sw];
    }
    const f32x4 zero = {0.f, 0.f, 0.f, 0.f};
    #pragma unroll
    for (int ks = 0; ks < 2; ++ks)
        #pragma unroll
        for (int fi = 0; fi < 4; ++fi)
            #pragma unroll
            for (int fj = 0; fj < 4; ++fj)
                acc[fi][fj] = __builtin_amdgcn_mfma_f32_16x16x32_f16(
                    a[fi][2 * H + ks], b[fj][ks],
                    (FIRST && ks == 0) ? zero : acc[fi][fj], 0, 0, 0);
}

__global__ __launch_bounds__(256) void dist_min_mfma(
        const _Float16* __restrict__ GAh, const _Float16* __restrict__ GBh,
        const float* __restrict__ x2, const float* __restrict__ y2,
        u64* __restrict__ packed) {
    __shared__ _Float16 smem[16384];   // 32 KiB: B0 | B1

    const int bid = blockIdx.x;
    const int c   = bid & 15;          // m-chunk; pinned to XCD c&7
    const int nt  = bid >> 4;          // 0..48
    const int n0  = nt * 128;
    const int mbase = c * 1024;

    const int tid  = threadIdx.x;
    const int lane = tid & 63;
    const int wid  = tid >> 6;
    const int wn = wid >> 1, wm = wid & 1;
    const int g = lane >> 4, r16 = lane & 15;
    const int srow = tid >> 2;
    const int se8  = (tid & 3) * 8;

    _Float16* sB0 = smem;
    _Float16* sB1 = smem + 8192;

    // issue first B half-tile immediately (async, no A dependency)
    stageB(GBh, sB0, mbase, 0, srow, se8);

    // A fragments: direct global->reg (same swizzled layout as LDS read had)
    f16x8 a[4][4];
    #pragma unroll
    for (int fi = 0; fi < 4; ++fi) {
        const int row = wn * 64 + fi * 16 + r16;
        const int sw = (g ^ ((row >> 1) & 3)) << 3;
        #pragma unroll
        for (int k = 0; k < 4; ++k)
            a[fi][k] = *(const f16x8*)(GAh + (size_t)(n0 + row) * DIMD + k * 32 + sw);
    }

    __syncthreads();                   // sB0 resident (vmcnt(0) drain)

    f32x4 acc[4][4];
    unsigned runkey[4][4];
    #pragma unroll
    for (int fi = 0; fi < 4; ++fi)
        #pragma unroll
        for (int r = 0; r < 4; ++r) runkey[fi][r] = 0xFFFFFFFFu;

    for (int t = 0; t < 8; ++t) {
        const int mt = mbase + t * 128;
        stageB(GBh, sB1, mt, 1, srow, se8);           // k-half 1 of tile t
        float ysb[4];
        #pragma unroll
        for (int fj = 0; fj < 4; ++fj)
            ysb[fj] = y2[mt + wm * 64 + fj * 16 + r16] + 512.f;
        computeB<0, true>(sB0, a, acc, wm, g, r16);
        __syncthreads();
        if (t < 7) stageB(GBh, sB0, mt + 128, 0, srow, se8);  // half 0 of t+1
        computeB<1, false>(sB1, a, acc, wm, g, r16);

        // fold tile t: biased value + 5-bit tag, u32 min
        const unsigned tag0 = (unsigned)(t * 4);
        #pragma unroll
        for (int fi = 0; fi < 4; ++fi)
            #pragma unroll
            for (int r = 0; r < 4; ++r) {
                unsigned k0 = (__float_as_uint(fmaf(-2.f, acc[fi][0][r], ysb[0])) & ~31u) | (tag0 + 0);
                unsigned k1 = (__float_as_uint(fmaf(-2.f, acc[fi][1][r], ysb[1])) & ~31u) | (tag0 + 1);
                unsigned k2 = (__float_as_uint(fmaf(-2.f, acc[fi][2][r], ysb[2])) & ~31u) | (tag0 + 2);
                unsigned k3 = (__float_as_uint(fmaf(-2.f, acc[fi][3][r], ysb[3])) & ~31u) | (tag0 + 3);
                unsigned km = min(min(k0, k1), min(k2, k3));
                runkey[fi][r] = min(runkey[fi][r], km);
            }
        __syncthreads();
    }

    // ---- epilogue: reconstruct m & d2, pack u64, 16-lane reduce, atomicMin --
    #pragma unroll
    for (int fi = 0; fi < 4; ++fi) {
        #pragma unroll
        for (int r = 0; r < 4; ++r) {
            const int n = n0 + wn * 64 + fi * 16 + g * 4 + r;
            const unsigned k = runkey[fi][r];
            const int tt = (k >> 2) & 7, j = k & 3;
            const int m = mbase + tt * 128 + wm * 64 + j * 16 + r16;
            float d2 = x2[n] + (__uint_as_float(k & ~31u) - 512.f);
            d2 = fmaxf(d2, EPSF);
            u64 best = ((u64)__float_as_uint(d2) << 32) | (unsigned)m;
            #pragma unroll
            for (int off = 1; off < 16; off <<= 1)
                best = umin64(best, (u64)__shfl_xor((unsigned long long)best, off));
            if (r16 == 0) atomicMin(&packed[n], best);
        }
    }
}

// ------- Phase C1: per-batch argmax of patch score + EXACT fp32 rescore -----
__global__ __launch_bounds__(256) void argmax_kernel(
        const u64* __restrict__ packed,
        const float* __restrict__ emb, const float* __restrict__ bank,
        const float* __restrict__ x2, const float* __restrict__ y2,
        uint4* __restrict__ binfo) {
    const int b = blockIdx.x, tid = threadIdx.x;
    __shared__ u64 red[256];
    __shared__ float fred[256];
    __shared__ unsigned s_p, s_nn;
    u64 bk = 0;
    for (int p = tid; p < PPB; p += 256) {
        u64 pk = packed[(size_t)b * PPB + p];
        unsigned d2b = (unsigned)(pk >> 32);
        u64 key = ((u64)d2b << 32) | (u64)(0xFFFFFFFFu - (unsigned)p);
        bk = umax64(bk, key);
    }
    red[tid] = bk; __syncthreads();
    for (int s = 128; s; s >>= 1) {
        if (tid < s) red[tid] = umax64(red[tid], red[tid + s]);
        __syncthreads();
    }
    if (tid == 0) {
        u64 w = red[0];
        unsigned p = 0xFFFFFFFFu - (unsigned)w;
        s_p = p;
        s_nn = (unsigned)packed[(size_t)b * PPB + p];
    }
    __syncthreads();
    const unsigned p = s_p, nn = s_nn;
    float prod = 0.f;
    if (tid < DIMD)
        prod = emb[(size_t)(b * PPB + p) * DIMD + tid] * bank[(size_t)nn * DIMD + tid];
    fred[tid] = prod; __syncthreads();
    for (int s = 128; s; s >>= 1) {
        if (tid < s) fred[tid] += fred[tid + s];
        __syncthreads();
    }
    if (tid == 0) {
        float d2 = x2[b * PPB + p] + y2[nn] - 2.0f * fred[0];
        binfo[b] = make_uint4(p, nn, __float_as_uint(fmaxf(d2, EPSF)), 0u);
    }
}

// ---------------- Phase C2: dist^2(nn_sample, bank) (exact fp32) ----------
__global__ void dnn_kernel(const float* __restrict__ bank,
                           const float* __restrict__ y2,
                           const uint4* __restrict__ binfo,
                           float* __restrict__ dnn) {
    const int b = blockIdx.y;
    const unsigned nn = binfo[b].y;
    __shared__ float nv[DIMD];
    if (threadIdx.x < DIMD) nv[threadIdx.x] = bank[(size_t)nn * DIMD + threadIdx.x];
    __syncthreads();
    const int m = blockIdx.x * 256 + threadIdx.x;
    const float4* row = (const float4*)(bank + (size_t)m * DIMD);
    float dot = 0.f;
    #pragma unroll
    for (int q = 0; q < DIMD / 4; ++q) {
        float4 v = row[q];
        dot += v.x * nv[q*4+0] + v.y * nv[q*4+1] + v.z * nv[q*4+2] + v.w * nv[q*4+3];
    }
    float d2 = y2[nn] + y2[m] - 2.0f * dot;
    dnn[(size_t)b * M_BANK + m] = fmaxf(d2, EPSF);
}

// ---------------- Phase C3: top-9 (reg lists + merge), softmax, output -----
__global__ __launch_bounds__(256) void final_kernel(
        const float* __restrict__ emb,
        const float* __restrict__ bank,
        const float* __restrict__ x2,
        const float* __restrict__ y2,
        const uint4* __restrict__ binfo,
        const float* __restrict__ dnn,
        float* __restrict__ out) {
    const int b = blockIdx.x, tid = threadIdx.x;
    __shared__ u64 lists[256 * KNN];   // 18 KiB
    __shared__ u64 red4[4];
    __shared__ u64 s_wkey;
    __shared__ unsigned s_sel[KNN];
    __shared__ float s_dist[KNN];
    __shared__ float xv[DIMD];

    const uint4 info = binfo[b];
    const unsigned nstar = info.x;
    const float d2star = __uint_as_float(info.z);
    if (tid < DIMD) xv[tid] = emb[(size_t)(b * PPB + nstar) * DIMD + tid];

    u64 lst[KNN];
    #pragma unroll
    for (int s = 0; s < KNN; ++s) lst[s] = ~0ull;
    for (int i = 0; i < M_BANK / 256; ++i) {
        const int m = tid + (i << 8);
        const float v = dnn[(size_t)b * M_BANK + m];
        const u64 key = ((u64)__float_as_uint(v) << 32) | (unsigned)m;
        if (key < lst[KNN - 1]) {
            lst[KNN - 1] = key;
            #pragma unroll
            for (int s = KNN - 1; s > 0; --s) {
                u64 a = lst[s - 1], cc = lst[s];
                lst[s - 1] = umin64(a, cc);
                lst[s]     = umax64(a, cc);
            }
        }
    }
    #pragma unroll
    for (int s = 0; s < KNN; ++s) lists[tid * KNN + s] = lst[s];
    __syncthreads();

    int p = 0;
    for (int r = 0; r < KNN; ++r) {
        u64 h = (p < KNN) ? lists[tid * KNN + p] : ~0ull;
        #pragma unroll
        for (int off = 1; off < 64; off <<= 1)
            h = umin64(h, (u64)__shfl_xor((unsigned long long)h, off));
        if ((tid & 63) == 0) red4[tid >> 6] = h;
        __syncthreads();
        if (tid == 0) {
            u64 w = umin64(umin64(red4[0], red4[1]), umin64(red4[2], red4[3]));
            s_wkey = w;
            s_sel[r] = (unsigned)w;
        }
        __syncthreads();
        const u64 w = s_wkey;
        if (p < KNN && lists[tid * KNN + p] == w) ++p;
    }

    if (tid < KNN) {
        const unsigned s = s_sel[tid];
        const float* srow = bank + (size_t)s * DIMD;
        float dot = 0.f;
        for (int d = 0; d < DIMD; ++d) dot += srow[d] * xv[d];
        float d2 = x2[b * PPB + nstar] + y2[s] - 2.0f * dot;
        s_dist[tid] = sqrtf(fmaxf(d2, EPSF));
    }
    __syncthreads();

    if (tid == 0) {
        float mx = s_dist[0];
        for (int i = 1; i < KNN; ++i) mx = fmaxf(mx, s_dist[i]);
        float sum = 0.f, e0 = 0.f;
        for (int i = 0; i < KNN; ++i) {
            float e = expf(s_dist[i] - mx);
            sum += e;
            if (i == 0) e0 = e;
        }
        float w = 1.0f - e0 / sum;
        out[b] = w * sqrtf(fmaxf(d2star, EPSF));
    }
}

extern "C" void kernel_launch(void* const* d_in, const int* in_sizes, int n_in,
                              void* d_out, int out_size, void* d_ws, size_t ws_size,
                              hipStream_t stream) {
    const float* emb  = (const float*)d_in[0];
    const float* bank = (const float*)d_in[1];
    float* out = (float*)d_out;

    char* ws = (char*)d_ws;
    u64*      packed = (u64*)      (ws + 0);         //  50176 B
    float*    x2     = (float*)    (ws + 65536);     //  25088 B
    float*    y2     = (float*)    (ws + 131072);    //  65536 B
    uint4*    binfo  = (uint4*)    (ws + 200704);    //    128 B
    float*    dnn    = (float*)    (ws + 262144);    // 524288 B
    _Float16* GAh    = (_Float16*) (ws + 786432);    // 1605632 B
    _Float16* GBh    = (_Float16*) (ws + 2392064);   // 4194304 B  (end 6586368)

    {
        const int rows = M_BANK + N_EMB;             // 22656
        const int blocks = rows * 16 / 256;          // 1416
        convert_kernel<<<blocks, 256, 0, stream>>>(emb, bank, GAh, GBh, x2, y2, packed);
    }

    dist_min_mfma<<<49 * 16, 256, 0, stream>>>(GAh, GBh, x2, y2, packed);

    argmax_kernel<<<BATCH, 256, 0, stream>>>(packed, emb, bank, x2, y2, binfo);

    dnn_kernel<<<dim3(M_BANK / 256, BATCH), 256, 0, stream>>>(bank, y2, binfo, dnn);

    final_kernel<<<BATCH, 256, 0, stream>>>(emb, bank, x2, y2, binfo, dnn, out);
}

// Round 9
// 141.673 us; speedup vs baseline: 1.0139x; 1.0139x over previous
//
#include <hip/hip_runtime.h>
#include <cstdint>

#define N_EMB 6272      // B*W*H = 8*28*28
#define DIMD  128
#define M_BANK 16384
#define BATCH 8
#define PPB   784       // patches per batch
#define KNN   9
#define EPSF  1e-12f

typedef unsigned long long u64;
typedef _Float16 f16x8 __attribute__((ext_vector_type(8)));
typedef float    f32x4 __attribute__((ext_vector_type(4)));

static __device__ __forceinline__ u64 umin64(u64 a, u64 b) { return b < a ? b : a; }
static __device__ __forceinline__ u64 umax64(u64 a, u64 b) { return b > a ? b : a; }

// ---------------- Phase A: convert f32 -> fp16 (straight copy) + exact norms
// Also initializes packed[] (replaces a separate memset dispatch).
__global__ __launch_bounds__(256) void convert_kernel(
        const float* __restrict__ emb, const float* __restrict__ bank,
        _Float16* __restrict__ GA, _Float16* __restrict__ GB,
        float* __restrict__ x2, float* __restrict__ y2,
        u64* __restrict__ packed) {
    const int gid = blockIdx.x * 256 + threadIdx.x;
    if (gid < N_EMB) packed[gid] = ~0ull;
    const int row = gid >> 4;
    const int chunk = gid & 15;
    const float* src;
    _Float16* dh;
    float* nrm;
    int R;
    if (row < M_BANK) {
        src = bank + (size_t)row * DIMD; dh = GB; nrm = y2; R = row;
    } else {
        R = row - M_BANK;
        src = emb + (size_t)R * DIMD; dh = GA; nrm = x2;
    }
    float4 v0 = ((const float4*)src)[chunk * 2];
    float4 v1 = ((const float4*)src)[chunk * 2 + 1];
    float f[8] = {v0.x, v0.y, v0.z, v0.w, v1.x, v1.y, v1.z, v1.w};
    f16x8 h;
    float s = 0.f;
    #pragma unroll
    for (int e = 0; e < 8; ++e) {
        h[e] = (_Float16)f[e];
        s += f[e] * f[e];
    }
    *(f16x8*)(dh + (size_t)R * DIMD + chunk * 8) = h;
    #pragma unroll
    for (int off = 1; off < 16; off <<= 1) s += __shfl_xor(s, off, 16);
    if (chunk == 0) nrm[R] = s;
}

// ---------------- Phase B: MFMA approx dist^2 + per-row min/argmin ----------
// Barrier-free, LDS-free: 1 wave per block. Each wave owns a 64-row A-strip
// (16 f16x8 in regs, loaded once) and streams 8 B-tiles of 64 rows direct
// global->reg (L2-resident, XCD-pinned). Per-tile acc (zero-C first MFMA),
// folded to a u32 running key: biased (+512) value, 5 low mantissa bits
// replaced by (t*4+fj) tag. Exact d2/index reconstructed in epilogue.
__global__ __launch_bounds__(64, 2) void dist_min_mfma(
        const _Float16* __restrict__ GA, const _Float16* __restrict__ GB,
        const float* __restrict__ x2, const float* __restrict__ y2,
        u64* __restrict__ packed) {
    const int bid = blockIdx.x;
    const int c   = bid & 31;          // m-chunk (512 rows); XCD = c&7
    const int s   = bid >> 5;          // n-strip (64 rows), 0..97
    const int n0  = s * 64;
    const int mbase = c * 512;

    const int lane = threadIdx.x;      // 0..63
    const int g = lane >> 4, r16 = lane & 15;

    // A fragments: 16 coalesced 16B loads, held in regs for the whole kernel
    f16x8 a[4][4];
    #pragma unroll
    for (int fi = 0; fi < 4; ++fi) {
        const _Float16* Arow = GA + (size_t)(n0 + fi * 16 + r16) * DIMD + g * 8;
        #pragma unroll
        for (int k = 0; k < 4; ++k)
            a[fi][k] = *(const f16x8*)(Arow + k * 32);
    }

    unsigned runkey[4][4];
    #pragma unroll
    for (int fi = 0; fi < 4; ++fi)
        #pragma unroll
        for (int r = 0; r < 4; ++r) runkey[fi][r] = 0xFFFFFFFFu;

    #pragma unroll 1
    for (int t = 0; t < 8; ++t) {
        const int mt = mbase + t * 64;

        f16x8 b[4][4];
        #pragma unroll
        for (int fj = 0; fj < 4; ++fj) {
            const _Float16* Brow = GB + (size_t)(mt + fj * 16 + r16) * DIMD + g * 8;
            #pragma unroll
            for (int k = 0; k < 4; ++k)
                b[fj][k] = *(const f16x8*)(Brow + k * 32);
        }
        float ysb[4];
        #pragma unroll
        for (int fj = 0; fj < 4; ++fj)
            ysb[fj] = y2[mt + fj * 16 + r16] + 512.f;

        f32x4 acc[4][4];
        const f32x4 zero = {0.f, 0.f, 0.f, 0.f};
        #pragma unroll
        for (int k = 0; k < 4; ++k)
            #pragma unroll
            for (int fi = 0; fi < 4; ++fi)
                #pragma unroll
                for (int fj = 0; fj < 4; ++fj)
                    acc[fi][fj] = __builtin_amdgcn_mfma_f32_16x16x32_f16(
                        a[fi][k], b[fj][k], k == 0 ? zero : acc[fi][fj], 0, 0, 0);

        const unsigned tag0 = (unsigned)(t * 4);
        #pragma unroll
        for (int fi = 0; fi < 4; ++fi)
            #pragma unroll
            for (int r = 0; r < 4; ++r) {
                unsigned k0 = (__float_as_uint(fmaf(-2.f, acc[fi][0][r], ysb[0])) & ~31u) | (tag0 + 0);
                unsigned k1 = (__float_as_uint(fmaf(-2.f, acc[fi][1][r], ysb[1])) & ~31u) | (tag0 + 1);
                unsigned k2 = (__float_as_uint(fmaf(-2.f, acc[fi][2][r], ysb[2])) & ~31u) | (tag0 + 2);
                unsigned k3 = (__float_as_uint(fmaf(-2.f, acc[fi][3][r], ysb[3])) & ~31u) | (tag0 + 3);
                unsigned km = min(min(k0, k1), min(k2, k3));
                runkey[fi][r] = min(runkey[fi][r], km);
            }
    }

    // ---- epilogue: reconstruct m & d2, pack u64, 16-lane reduce, atomicMin --
    #pragma unroll
    for (int fi = 0; fi < 4; ++fi) {
        #pragma unroll
        for (int r = 0; r < 4; ++r) {
            const int n = n0 + fi * 16 + g * 4 + r;
            const unsigned k = runkey[fi][r];
            const int tt = (k >> 2) & 7, j = k & 3;
            const int m = mbase + tt * 64 + j * 16 + r16;
            float d2 = x2[n] + (__uint_as_float(k & ~31u) - 512.f);
            d2 = fmaxf(d2, EPSF);
            u64 best = ((u64)__float_as_uint(d2) << 32) | (unsigned)m;
            #pragma unroll
            for (int off = 1; off < 16; off <<= 1)
                best = umin64(best, (u64)__shfl_xor((unsigned long long)best, off));
            if (r16 == 0) atomicMin(&packed[n], best);
        }
    }
}

// ------- Phase C1: per-batch argmax of patch score + EXACT fp32 rescore -----
__global__ __launch_bounds__(256) void argmax_kernel(
        const u64* __restrict__ packed,
        const float* __restrict__ emb, const float* __restrict__ bank,
        const float* __restrict__ x2, const float* __restrict__ y2,
        uint4* __restrict__ binfo) {
    const int b = blockIdx.x, tid = threadIdx.x;
    __shared__ u64 red[256];
    __shared__ float fred[256];
    __shared__ unsigned s_p, s_nn;
    u64 bk = 0;
    for (int p = tid; p < PPB; p += 256) {
        u64 pk = packed[(size_t)b * PPB + p];
        unsigned d2b = (unsigned)(pk >> 32);
        u64 key = ((u64)d2b << 32) | (u64)(0xFFFFFFFFu - (unsigned)p);
        bk = umax64(bk, key);
    }
    red[tid] = bk; __syncthreads();
    for (int s = 128; s; s >>= 1) {
        if (tid < s) red[tid] = umax64(red[tid], red[tid + s]);
        __syncthreads();
    }
    if (tid == 0) {
        u64 w = red[0];
        unsigned p = 0xFFFFFFFFu - (unsigned)w;
        s_p = p;
        s_nn = (unsigned)packed[(size_t)b * PPB + p];
    }
    __syncthreads();
    const unsigned p = s_p, nn = s_nn;
    float prod = 0.f;
    if (tid < DIMD)
        prod = emb[(size_t)(b * PPB + p) * DIMD + tid] * bank[(size_t)nn * DIMD + tid];
    fred[tid] = prod; __syncthreads();
    for (int s = 128; s; s >>= 1) {
        if (tid < s) fred[tid] += fred[tid + s];
        __syncthreads();
    }
    if (tid == 0) {
        float d2 = x2[b * PPB + p] + y2[nn] - 2.0f * fred[0];
        binfo[b] = make_uint4(p, nn, __float_as_uint(fmaxf(d2, EPSF)), 0u);
    }
}

// ---------------- Phase C2: dist^2(nn_sample, bank) (exact fp32) ----------
__global__ void dnn_kernel(const float* __restrict__ bank,
                           const float* __restrict__ y2,
                           const uint4* __restrict__ binfo,
                           float* __restrict__ dnn) {
    const int b = blockIdx.y;
    const unsigned nn = binfo[b].y;
    __shared__ float nv[DIMD];
    if (threadIdx.x < DIMD) nv[threadIdx.x] = bank[(size_t)nn * DIMD + threadIdx.x];
    __syncthreads();
    const int m = blockIdx.x * 256 + threadIdx.x;
    const float4* row = (const float4*)(bank + (size_t)m * DIMD);
    float dot = 0.f;
    #pragma unroll
    for (int q = 0; q < DIMD / 4; ++q) {
        float4 v = row[q];
        dot += v.x * nv[q*4+0] + v.y * nv[q*4+1] + v.z * nv[q*4+2] + v.w * nv[q*4+3];
    }
    float d2 = y2[nn] + y2[m] - 2.0f * dot;
    dnn[(size_t)b * M_BANK + m] = fmaxf(d2, EPSF);
}

// ---------------- Phase C3: top-9 (reg lists + merge), softmax, output -----
__global__ __launch_bounds__(256) void final_kernel(
        const float* __restrict__ emb,
        const float* __restrict__ bank,
        const float* __restrict__ x2,
        const float* __restrict__ y2,
        const uint4* __restrict__ binfo,
        const float* __restrict__ dnn,
        float* __restrict__ out) {
    const int b = blockIdx.x, tid = threadIdx.x;
    __shared__ u64 lists[256 * KNN];   // 18 KiB
    __shared__ u64 red4[4];
    __shared__ u64 s_wkey;
    __shared__ unsigned s_sel[KNN];
    __shared__ float s_dist[KNN];
    __shared__ float xv[DIMD];

    const uint4 info = binfo[b];
    const unsigned nstar = info.x;
    const float d2star = __uint_as_float(info.z);
    if (tid < DIMD) xv[tid] = emb[(size_t)(b * PPB + nstar) * DIMD + tid];

    u64 lst[KNN];
    #pragma unroll
    for (int s = 0; s < KNN; ++s) lst[s] = ~0ull;
    for (int i = 0; i < M_BANK / 256; ++i) {
        const int m = tid + (i << 8);
        const float v = dnn[(size_t)b * M_BANK + m];
        const u64 key = ((u64)__float_as_uint(v) << 32) | (unsigned)m;
        if (key < lst[KNN - 1]) {
            lst[KNN - 1] = key;
            #pragma unroll
            for (int s = KNN - 1; s > 0; --s) {
                u64 a = lst[s - 1], cc = lst[s];
                lst[s - 1] = umin64(a, cc);
                lst[s]     = umax64(a, cc);
            }
        }
    }
    #pragma unroll
    for (int s = 0; s < KNN; ++s) lists[tid * KNN + s] = lst[s];
    __syncthreads();

    int p = 0;
    for (int r = 0; r < KNN; ++r) {
        u64 h = (p < KNN) ? lists[tid * KNN + p] : ~0ull;
        #pragma unroll
        for (int off = 1; off < 64; off <<= 1)
            h = umin64(h, (u64)__shfl_xor((unsigned long long)h, off));
        if ((tid & 63) == 0) red4[tid >> 6] = h;
        __syncthreads();
        if (tid == 0) {
            u64 w = umin64(umin64(red4[0], red4[1]), umin64(red4[2], red4[3]));
            s_wkey = w;
            s_sel[r] = (unsigned)w;
        }
        __syncthreads();
        const u64 w = s_wkey;
        if (p < KNN && lists[tid * KNN + p] == w) ++p;
    }

    if (tid < KNN) {
        const unsigned s = s_sel[tid];
        const float* srow = bank + (size_t)s * DIMD;
        float dot = 0.f;
        for (int d = 0; d < DIMD; ++d) dot += srow[d] * xv[d];
        float d2 = x2[b * PPB + nstar] + y2[s] - 2.0f * dot;
        s_dist[tid] = sqrtf(fmaxf(d2, EPSF));
    }
    __syncthreads();

    if (tid == 0) {
        float mx = s_dist[0];
        for (int i = 1; i < KNN; ++i) mx = fmaxf(mx, s_dist[i]);
        float sum = 0.f, e0 = 0.f;
        for (int i = 0; i < KNN; ++i) {
            float e = expf(s_dist[i] - mx);
            sum += e;
            if (i == 0) e0 = e;
        }
        float w = 1.0f - e0 / sum;
        out[b] = w * sqrtf(fmaxf(d2star, EPSF));
    }
}

extern "C" void kernel_launch(void* const* d_in, const int* in_sizes, int n_in,
                              void* d_out, int out_size, void* d_ws, size_t ws_size,
                              hipStream_t stream) {
    const float* emb  = (const float*)d_in[0];
    const float* bank = (const float*)d_in[1];
    float* out = (float*)d_out;

    char* ws = (char*)d_ws;
    u64*      packed = (u64*)      (ws + 0);         //  50176 B
    float*    x2     = (float*)    (ws + 65536);     //  25088 B
    float*    y2     = (float*)    (ws + 131072);    //  65536 B
    uint4*    binfo  = (uint4*)    (ws + 200704);    //    128 B
    float*    dnn    = (float*)    (ws + 262144);    // 524288 B
    _Float16* GA     = (_Float16*) (ws + 786432);    // 1605632 B
    _Float16* GB     = (_Float16*) (ws + 2392064);   // 4194304 B  (end 6586368)

    {
        const int rows = M_BANK + N_EMB;             // 22656
        const int blocks = rows * 16 / 256;          // 1416
        convert_kernel<<<blocks, 256, 0, stream>>>(emb, bank, GA, GB, x2, y2, packed);
    }

    dist_min_mfma<<<98 * 32, 64, 0, stream>>>(GA, GB, x2, y2, packed);

    argmax_kernel<<<BATCH, 256, 0, stream>>>(packed, emb, bank, x2, y2, binfo);

    dnn_kernel<<<dim3(M_BANK / 256, BATCH), 256, 0, stream>>>(bank, y2, binfo, dnn);

    final_kernel<<<BATCH, 256, 0, stream>>>(emb, bank, x2, y2, binfo, dnn, out);
}

// Round 10
// 141.091 us; speedup vs baseline: 1.0180x; 1.0041x over previous
//
#include <hip/hip_runtime.h>
#include <cstdint>

#define N_EMB 6272      // B*W*H = 8*28*28
#define DIMD  128
#define M_BANK 16384
#define BATCH 8
#define PPB   784       // patches per batch
#define KNN   9
#define EPSF  1e-12f

typedef unsigned long long u64;
typedef _Float16 f16x8 __attribute__((ext_vector_type(8)));
typedef float    f32x4 __attribute__((ext_vector_type(4)));

static __device__ __forceinline__ u64 umin64(u64 a, u64 b) { return b < a ? b : a; }
static __device__ __forceinline__ u64 umax64(u64 a, u64 b) { return b > a ? b : a; }

// async global->LDS, 16B per lane, linear LDS dest (wave-uniform base + lane*16)
static __device__ __forceinline__ void gll16(const _Float16* g, _Float16* l) {
    __builtin_amdgcn_global_load_lds(
        (__attribute__((address_space(1))) void*)(const void*)g,
        (__attribute__((address_space(3))) void*)l, 16, 0, 0);
}

// ---------------- Phase A: convert f32 -> fp16 (pre-swizzled) + exact norms --
// Pre-swizzle within each 32-col quarter q: out chunk jj' = jj ^ ((row>>1)&3).
// Also initializes packed[].
__global__ __launch_bounds__(256) void convert_kernel(
        const float* __restrict__ emb, const float* __restrict__ bank,
        _Float16* __restrict__ GAh, _Float16* __restrict__ GBh,
        float* __restrict__ x2, float* __restrict__ y2,
        u64* __restrict__ packed) {
    const int gid = blockIdx.x * 256 + threadIdx.x;
    if (gid < N_EMB) packed[gid] = ~0ull;
    const int row = gid >> 4;
    const int chunk = gid & 15;
    const float* src;
    _Float16* dh;
    float* nrm;
    int R;
    if (row < M_BANK) {
        src = bank + (size_t)row * DIMD; dh = GBh; nrm = y2; R = row;
    } else {
        R = row - M_BANK;
        src = emb + (size_t)R * DIMD; dh = GAh; nrm = x2;
    }
    float4 v0 = ((const float4*)src)[chunk * 2];
    float4 v1 = ((const float4*)src)[chunk * 2 + 1];
    float f[8] = {v0.x, v0.y, v0.z, v0.w, v1.x, v1.y, v1.z, v1.w};
    f16x8 h;
    float s = 0.f;
    #pragma unroll
    for (int e = 0; e < 8; ++e) {
        h[e] = (_Float16)f[e];
        s += f[e] * f[e];
    }
    const int q = chunk >> 2, jj = chunk & 3;
    const int jj2 = jj ^ ((R >> 1) & 3);
    *(f16x8*)(dh + (size_t)R * DIMD + q * 32 + jj2 * 8) = h;
    #pragma unroll
    for (int off = 1; off < 16; off <<= 1) s += __shfl_xor(s, off, 16);
    if (chunk == 0) nrm[R] = s;
}

// ---------------- Phase B: MFMA approx dist^2 + per-row min/argmin ----------
// r5 structure (best measured): 128x128 tile, 4 waves (2x2 quadrants),
// A in regs (staged via LDS once), B double-buffered, BK=64, 2 phases/tile.
// Deltas vs r5: 32KB LDS (A-region reused as B dbuf), zero-C first MFMA,
// cheap u32 tag-fold (biased +512, 5 low mantissa bits -> (t*4+fj) tag).

static __device__ __forceinline__ void stageB(
        const _Float16* __restrict__ GBh, _Float16* dst,
        int mrow0, int h, int srow, int se8) {
    #pragma unroll
    for (int j = 0; j < 2; ++j) {
        const int row = srow + j * 64;
        #pragma unroll
        for (int q = 0; q < 2; ++q)
            gll16(GBh + (size_t)(mrow0 + row) * DIMD + h * 64 + q * 32 + se8,
                  dst + q * 4096 + row * 32 + se8);
    }
}

template<int H, bool FIRST>
static __device__ __forceinline__ void computeB(
        const _Float16* bb, const f16x8 (&a)[4][4], f32x4 (&acc)[4][4],
        int wm, int g, int r16) {
    f16x8 b[4][2];
    #pragma unroll
    for (int fj = 0; fj < 4; ++fj) {
        const int row = wm * 64 + fj * 16 + r16;
        const int sw = (g ^ ((row >> 1) & 3)) << 3;
        b[fj][0] = *(const f16x8*)&bb[row * 32 + sw];
        b[fj][1] = *(const f16x8*)&bb[4096 + row * 32 + sw];
    }
    const f32x4 zero = {0.f, 0.f, 0.f, 0.f};
    #pragma unroll
    for (int ks = 0; ks < 2; ++ks)
        #pragma unroll
        for (int fi = 0; fi < 4; ++fi)
            #pragma unroll
            for (int fj = 0; fj < 4; ++fj)
                acc[fi][fj] = __builtin_amdgcn_mfma_f32_16x16x32_f16(
                    a[fi][2 * H + ks], b[fj][ks],
                    (FIRST && ks == 0) ? zero : acc[fi][fj], 0, 0, 0);
}

__global__ __launch_bounds__(256) void dist_min_mfma(
        const _Float16* __restrict__ GAh, const _Float16* __restrict__ GBh,
        const float* __restrict__ x2, const float* __restrict__ y2,
        u64* __restrict__ packed) {
    __shared__ _Float16 smem[16384];   // 32 KiB: A-stage, then B0 | B1

    const int bid = blockIdx.x;
    const int c   = bid & 15;          // m-chunk; pinned to XCD c&7
    const int nt  = bid >> 4;          // 0..48
    const int n0  = nt * 128;
    const int mbase = c * 1024;

    const int tid  = threadIdx.x;
    const int lane = tid & 63;
    const int wid  = tid >> 6;
    const int wn = wid >> 1, wm = wid & 1;
    const int g = lane >> 4, r16 = lane & 15;
    const int srow = tid >> 2;
    const int se8  = (tid & 3) * 8;

    _Float16* sB0 = smem;
    _Float16* sB1 = smem + 8192;

    // ---- prologue: stage A (32 KB), read to regs, then reuse LDS for B ----
    #pragma unroll
    for (int k = 0; k < 4; ++k)
        #pragma unroll
        for (int j = 0; j < 2; ++j) {
            const int row = srow + j * 64;
            gll16(GAh + (size_t)(n0 + row) * DIMD + k * 32 + se8,
                  smem + k * 4096 + row * 32 + se8);
        }
    __syncthreads();

    f16x8 a[4][4];
    #pragma unroll
    for (int fi = 0; fi < 4; ++fi) {
        const int row = wn * 64 + fi * 16 + r16;
        const int sw = (g ^ ((row >> 1) & 3)) << 3;
        #pragma unroll
        for (int k = 0; k < 4; ++k)
            a[fi][k] = *(const f16x8*)&smem[k * 4096 + row * 32 + sw];
    }
    __syncthreads();                       // everyone done reading A region

    stageB(GBh, sB0, mbase, 0, srow, se8); // first half-tile
    __syncthreads();                       // drain -> sB0 resident

    f32x4 acc[4][4];
    unsigned runkey[4][4];
    #pragma unroll
    for (int fi = 0; fi < 4; ++fi)
        #pragma unroll
        for (int r = 0; r < 4; ++r) runkey[fi][r] = 0xFFFFFFFFu;

    for (int t = 0; t < 8; ++t) {
        const int mt = mbase + t * 128;
        stageB(GBh, sB1, mt, 1, srow, se8);           // k-half 1 of tile t
        float ysb[4];
        #pragma unroll
        for (int fj = 0; fj < 4; ++fj)
            ysb[fj] = y2[mt + wm * 64 + fj * 16 + r16] + 512.f;
        computeB<0, true>(sB0, a, acc, wm, g, r16);
        __syncthreads();
        if (t < 7) stageB(GBh, sB0, mt + 128, 0, srow, se8);  // half 0 of t+1
        computeB<1, false>(sB1, a, acc, wm, g, r16);

        // fold tile t: biased value + 5-bit tag, u32 min
        const unsigned tag0 = (unsigned)(t * 4);
        #pragma unroll
        for (int fi = 0; fi < 4; ++fi)
            #pragma unroll
            for (int r = 0; r < 4; ++r) {
                unsigned k0 = (__float_as_uint(fmaf(-2.f, acc[fi][0][r], ysb[0])) & ~31u) | (tag0 + 0);
                unsigned k1 = (__float_as_uint(fmaf(-2.f, acc[fi][1][r], ysb[1])) & ~31u) | (tag0 + 1);
                unsigned k2 = (__float_as_uint(fmaf(-2.f, acc[fi][2][r], ysb[2])) & ~31u) | (tag0 + 2);
                unsigned k3 = (__float_as_uint(fmaf(-2.f, acc[fi][3][r], ysb[3])) & ~31u) | (tag0 + 3);
                unsigned km = min(min(k0, k1), min(k2, k3));
                runkey[fi][r] = min(runkey[fi][r], km);
            }
        __syncthreads();
    }

    // ---- epilogue: reconstruct m & d2, pack u64, 16-lane reduce, atomicMin --
    #pragma unroll
    for (int fi = 0; fi < 4; ++fi) {
        #pragma unroll
        for (int r = 0; r < 4; ++r) {
            const int n = n0 + wn * 64 + fi * 16 + g * 4 + r;
            const unsigned k = runkey[fi][r];
            const int tt = (k >> 2) & 7, j = k & 3;
            const int m = mbase + tt * 128 + wm * 64 + j * 16 + r16;
            float d2 = x2[n] + (__uint_as_float(k & ~31u) - 512.f);
            d2 = fmaxf(d2, EPSF);
            u64 best = ((u64)__float_as_uint(d2) << 32) | (unsigned)m;
            #pragma unroll
            for (int off = 1; off < 16; off <<= 1)
                best = umin64(best, (u64)__shfl_xor((unsigned long long)best, off));
            if (r16 == 0) atomicMin(&packed[n], best);
        }
    }
}

// ------- Phase C1: per-batch argmax of patch score + EXACT fp32 rescore -----
__global__ __launch_bounds__(256) void argmax_kernel(
        const u64* __restrict__ packed,
        const float* __restrict__ emb, const float* __restrict__ bank,
        const float* __restrict__ x2, const float* __restrict__ y2,
        uint4* __restrict__ binfo) {
    const int b = blockIdx.x, tid = threadIdx.x;
    __shared__ u64 red[256];
    __shared__ float fred[256];
    __shared__ unsigned s_p, s_nn;
    u64 bk = 0;
    for (int p = tid; p < PPB; p += 256) {
        u64 pk = packed[(size_t)b * PPB + p];
        unsigned d2b = (unsigned)(pk >> 32);
        u64 key = ((u64)d2b << 32) | (u64)(0xFFFFFFFFu - (unsigned)p);
        bk = umax64(bk, key);
    }
    red[tid] = bk; __syncthreads();
    for (int s = 128; s; s >>= 1) {
        if (tid < s) red[tid] = umax64(red[tid], red[tid + s]);
        __syncthreads();
    }
    if (tid == 0) {
        u64 w = red[0];
        unsigned p = 0xFFFFFFFFu - (unsigned)w;
        s_p = p;
        s_nn = (unsigned)packed[(size_t)b * PPB + p];
    }
    __syncthreads();
    const unsigned p = s_p, nn = s_nn;
    float prod = 0.f;
    if (tid < DIMD)
        prod = emb[(size_t)(b * PPB + p) * DIMD + tid] * bank[(size_t)nn * DIMD + tid];
    fred[tid] = prod; __syncthreads();
    for (int s = 128; s; s >>= 1) {
        if (tid < s) fred[tid] += fred[tid + s];
        __syncthreads();
    }
    if (tid == 0) {
        float d2 = x2[b * PPB + p] + y2[nn] - 2.0f * fred[0];
        binfo[b] = make_uint4(p, nn, __float_as_uint(fmaxf(d2, EPSF)), 0u);
    }
}

// --------- Phase C2: approx dist^2(nn_sample, bank) from fp16 GB -----------
// Selection-only (final distances are exactly rescored in final_kernel).
// GB rows are quarter-swizzled per row; XOR-align chunks: delta = s_nn ^ s_m.
__global__ __launch_bounds__(256) void dnn_kernel(
        const _Float16* __restrict__ GBh,
        const float* __restrict__ y2,
        const uint4* __restrict__ binfo,
        float* __restrict__ dnn) {
    const int b = blockIdx.y;
    const unsigned nn = binfo[b].y;
    __shared__ _Float16 nv[DIMD];      // stored-order chunks of row nn
    if (threadIdx.x < DIMD) nv[threadIdx.x] = GBh[(size_t)nn * DIMD + threadIdx.x];
    __syncthreads();
    const int m = blockIdx.x * 256 + threadIdx.x;
    const int delta = (((nn >> 1) ^ (m >> 1)) & 3);
    const _Float16* row = GBh + (size_t)m * DIMD;
    float dot = 0.f;
    #pragma unroll
    for (int q = 0; q < 4; ++q)
        #pragma unroll
        for (int jj2 = 0; jj2 < 4; ++jj2) {
            f16x8 ym = *(const f16x8*)(row + q * 32 + jj2 * 8);
            f16x8 xm = *(const f16x8*)&nv[q * 32 + (jj2 ^ delta) * 8];
            #pragma unroll
            for (int e = 0; e < 8; ++e)
                dot += (float)ym[e] * (float)xm[e];
        }
    float d2 = y2[nn] + y2[m] - 2.0f * dot;
    dnn[(size_t)b * M_BANK + m] = fmaxf(d2, EPSF);
}

// ---------------- Phase C3: top-9 (reg lists + merge), softmax, output -----
__global__ __launch_bounds__(256) void final_kernel(
        const float* __restrict__ emb,
        const float* __restrict__ bank,
        const float* __restrict__ x2,
        const float* __restrict__ y2,
        const uint4* __restrict__ binfo,
        const float* __restrict__ dnn,
        float* __restrict__ out) {
    const int b = blockIdx.x, tid = threadIdx.x;
    __shared__ u64 lists[256 * KNN];   // 18 KiB
    __shared__ u64 red4[4];
    __shared__ u64 s_wkey;
    __shared__ unsigned s_sel[KNN];
    __shared__ float s_dist[KNN];
    __shared__ float xv[DIMD];

    const uint4 info = binfo[b];
    const unsigned nstar = info.x;
    const float d2star = __uint_as_float(info.z);
    if (tid < DIMD) xv[tid] = emb[(size_t)(b * PPB + nstar) * DIMD + tid];

    u64 lst[KNN];
    #pragma unroll
    for (int s = 0; s < KNN; ++s) lst[s] = ~0ull;
    for (int i = 0; i < M_BANK / 256; ++i) {
        const int m = tid + (i << 8);
        const float v = dnn[(size_t)b * M_BANK + m];
        const u64 key = ((u64)__float_as_uint(v) << 32) | (unsigned)m;
        if (key < lst[KNN - 1]) {
            lst[KNN - 1] = key;
            #pragma unroll
            for (int s = KNN - 1; s > 0; --s) {
                u64 a = lst[s - 1], cc = lst[s];
                lst[s - 1] = umin64(a, cc);
                lst[s]     = umax64(a, cc);
            }
        }
    }
    #pragma unroll
    for (int s = 0; s < KNN; ++s) lists[tid * KNN + s] = lst[s];
    __syncthreads();

    int p = 0;
    for (int r = 0; r < KNN; ++r) {
        u64 h = (p < KNN) ? lists[tid * KNN + p] : ~0ull;
        #pragma unroll
        for (int off = 1; off < 64; off <<= 1)
            h = umin64(h, (u64)__shfl_xor((unsigned long long)h, off));
        if ((tid & 63) == 0) red4[tid >> 6] = h;
        __syncthreads();
        if (tid == 0) {
            u64 w = umin64(umin64(red4[0], red4[1]), umin64(red4[2], red4[3]));
            s_wkey = w;
            s_sel[r] = (unsigned)w;
        }
        __syncthreads();
        const u64 w = s_wkey;
        if (p < KNN && lists[tid * KNN + p] == w) ++p;
    }

    // exact fp32 distances for the 9 selected (order of 1..8 irrelevant:
    // output uses element 0 (self-match) + order-invariant sum)
    if (tid < KNN) {
        const unsigned s = s_sel[tid];
        const float* srow = bank + (size_t)s * DIMD;
        float dot = 0.f;
        for (int d = 0; d < DIMD; ++d) dot += srow[d] * xv[d];
        float d2 = x2[b * PPB + nstar] + y2[s] - 2.0f * dot;
        s_dist[tid] = sqrtf(fmaxf(d2, EPSF));
    }
    __syncthreads();

    if (tid == 0) {
        float mx = s_dist[0];
        for (int i = 1; i < KNN; ++i) mx = fmaxf(mx, s_dist[i]);
        float sum = 0.f, e0 = 0.f;
        for (int i = 0; i < KNN; ++i) {
            float e = expf(s_dist[i] - mx);
            sum += e;
            if (i == 0) e0 = e;
        }
        float w = 1.0f - e0 / sum;
        out[b] = w * sqrtf(fmaxf(d2star, EPSF));
    }
}

extern "C" void kernel_launch(void* const* d_in, const int* in_sizes, int n_in,
                              void* d_out, int out_size, void* d_ws, size_t ws_size,
                              hipStream_t stream) {
    const float* emb  = (const float*)d_in[0];
    const float* bank = (const float*)d_in[1];
    float* out = (float*)d_out;

    char* ws = (char*)d_ws;
    u64*      packed = (u64*)      (ws + 0);         //  50176 B
    float*    x2     = (float*)    (ws + 65536);     //  25088 B
    float*    y2     = (float*)    (ws + 131072);    //  65536 B
    uint4*    binfo  = (uint4*)    (ws + 200704);    //    128 B
    float*    dnn    = (float*)    (ws + 262144);    // 524288 B
    _Float16* GAh    = (_Float16*) (ws + 786432);    // 1605632 B
    _Float16* GBh    = (_Float16*) (ws + 2392064);   // 4194304 B  (end 6586368)

    {
        const int rows = M_BANK + N_EMB;             // 22656
        const int blocks = rows * 16 / 256;          // 1416
        convert_kernel<<<blocks, 256, 0, stream>>>(emb, bank, GAh, GBh, x2, y2, packed);
    }

    dist_min_mfma<<<49 * 16, 256, 0, stream>>>(GAh, GBh, x2, y2, packed);

    argmax_kernel<<<BATCH, 256, 0, stream>>>(packed, emb, bank, x2, y2, binfo);

    dnn_kernel<<<dim3(M_BANK / 256, BATCH), 256, 0, stream>>>(GBh, y2, binfo, dnn);

    final_kernel<<<BATCH, 256, 0, stream>>>(emb, bank, x2, y2, binfo, dnn, out);
}

// Round 11
// 105.515 us; speedup vs baseline: 1.3613x; 1.3372x over previous
//
#include <hip/hip_runtime.h>
#include <cstdint>

#define N_EMB 6272      // B*W*H = 8*28*28
#define DIMD  128
#define M_BANK 16384
#define BATCH 8
#define PPB   784       // patches per batch
#define KNN   9
#define EPSF  1e-12f

typedef unsigned long long u64;
typedef _Float16 f16x8 __attribute__((ext_vector_type(8)));
typedef float    f32x4 __attribute__((ext_vector_type(4)));

static __device__ __forceinline__ u64 umin64(u64 a, u64 b) { return b < a ? b : a; }
static __device__ __forceinline__ u64 umax64(u64 a, u64 b) { return b > a ? b : a; }

// async global->LDS, 16B per lane, linear LDS dest (wave-uniform base + lane*16)
static __device__ __forceinline__ void gll16(const _Float16* g, _Float16* l) {
    __builtin_amdgcn_global_load_lds(
        (__attribute__((address_space(1))) void*)(const void*)g,
        (__attribute__((address_space(3))) void*)l, 16, 0, 0);
}

// ---------------- Phase A: convert f32 -> fp16 (pre-swizzled) + exact norms --
// Also initializes packed[] (replaces a separate memset dispatch).
__global__ __launch_bounds__(256) void convert_kernel(
        const float* __restrict__ emb, const float* __restrict__ bank,
        _Float16* __restrict__ GAh, _Float16* __restrict__ GBh,
        float* __restrict__ x2, float* __restrict__ y2,
        u64* __restrict__ packed) {
    const int gid = blockIdx.x * 256 + threadIdx.x;
    if (gid < N_EMB) packed[gid] = ~0ull;
    const int row = gid >> 4;
    const int chunk = gid & 15;
    const float* src;
    _Float16* dh;
    float* nrm;
    int R;
    if (row < M_BANK) {
        src = bank + (size_t)row * DIMD; dh = GBh; nrm = y2; R = row;
    } else {
        R = row - M_BANK;
        src = emb + (size_t)R * DIMD; dh = GAh; nrm = x2;
    }
    float4 v0 = ((const float4*)src)[chunk * 2];
    float4 v1 = ((const float4*)src)[chunk * 2 + 1];
    float f[8] = {v0.x, v0.y, v0.z, v0.w, v1.x, v1.y, v1.z, v1.w};
    f16x8 h;
    float s = 0.f;
    #pragma unroll
    for (int e = 0; e < 8; ++e) {
        h[e] = (_Float16)f[e];
        s += f[e] * f[e];
    }
    const int q = chunk >> 2, jj = chunk & 3;
    const int jj2 = jj ^ ((R >> 1) & 3);
    *(f16x8*)(dh + (size_t)R * DIMD + q * 32 + jj2 * 8) = h;
    #pragma unroll
    for (int off = 1; off < 16; off <<= 1) s += __shfl_xor(s, off, 16);
    if (chunk == 0) nrm[R] = s;
}

// ---------------- Phase B: MFMA approx dist^2 + per-row min/argmin ----------
// MEASURED-BEST (round-5, 53.5 us) configuration -- restored byte-identical.
// A-in-registers persistent-m: grid = 49 n-tiles x 16 m-chunks, 4 waves/block,
// A (128 x K128) staged via LDS once -> 16 f16x8 regs/wave; B double-buffered
// in separate 2x16KB LDS; BK=64, 2 phases/tile.
// NOTE (r10 lesson): the "heavy" per-tile fold below is load-latency COVER --
// it sits between the stageB issue and the barrier's vmcnt(0) drain. Making it
// cheaper (r10 tag-fold) exposed the drain and cost +36 us. Do not "optimize".
// VGPR lands at exactly 128 (4 waves/SIMD boundary); LDS 64KB -> 2 blocks/CU.

static __device__ __forceinline__ void stageB(
        const _Float16* __restrict__ GBh, _Float16* dst,
        int mrow0, int h, int srow, int se8) {
    #pragma unroll
    for (int j = 0; j < 2; ++j) {
        const int row = srow + j * 64;
        #pragma unroll
        for (int q = 0; q < 2; ++q)
            gll16(GBh + (size_t)(mrow0 + row) * DIMD + h * 64 + q * 32 + se8,
                  dst + q * 4096 + row * 32 + se8);
    }
}

template<int H>
static __device__ __forceinline__ void computeB(
        const _Float16* bb, const f16x8 (&a)[4][4], f32x4 (&acc)[4][4],
        int wm, int g, int r16) {
    f16x8 b[4][2];
    #pragma unroll
    for (int fj = 0; fj < 4; ++fj) {
        const int row = wm * 64 + fj * 16 + r16;
        const int sw = (g ^ ((row >> 1) & 3)) << 3;
        b[fj][0] = *(const f16x8*)&bb[row * 32 + sw];
        b[fj][1] = *(const f16x8*)&bb[4096 + row * 32 + sw];
    }
    #pragma unroll
    for (int ks = 0; ks < 2; ++ks)
        #pragma unroll
        for (int fi = 0; fi < 4; ++fi)
            #pragma unroll
            for (int fj = 0; fj < 4; ++fj)
                acc[fi][fj] = __builtin_amdgcn_mfma_f32_16x16x32_f16(
                    a[fi][2 * H + ks], b[fj][ks], acc[fi][fj], 0, 0, 0);
}

__global__ __launch_bounds__(256, 2) void dist_min_mfma(
        const _Float16* __restrict__ GAh, const _Float16* __restrict__ GBh,
        const float* __restrict__ x2, const float* __restrict__ y2,
        u64* __restrict__ packed) {
    __shared__ _Float16 smem[32768];   // 64 KiB: A[4][128][32] | B0 | B1

    const int bid = blockIdx.x;
    const int c   = bid & 15;          // m-chunk; all its blocks on XCD c&7
    const int nt  = bid >> 4;          // 0..48
    const int n0  = nt * 128;
    const int mbase = c * 1024;

    const int tid  = threadIdx.x;
    const int lane = tid & 63;
    const int wid  = tid >> 6;
    const int wn = wid >> 1, wm = wid & 1;
    const int g = lane >> 4, r16 = lane & 15;
    const int srow = tid >> 2;
    const int se8  = (tid & 3) * 8;

    _Float16* sB0 = smem + 16384;
    _Float16* sB1 = smem + 24576;

    // ---- prologue: stage A (32 KB) + B(t=0, h=0) ----
    #pragma unroll
    for (int k = 0; k < 4; ++k)
        #pragma unroll
        for (int j = 0; j < 2; ++j) {
            const int row = srow + j * 64;
            gll16(GAh + (size_t)(n0 + row) * DIMD + k * 32 + se8,
                  smem + k * 4096 + row * 32 + se8);
        }
    stageB(GBh, sB0, mbase, 0, srow, se8);

    float xs[4][4];
    #pragma unroll
    for (int fi = 0; fi < 4; ++fi)
        #pragma unroll
        for (int r = 0; r < 4; ++r)
            xs[fi][r] = x2[n0 + wn * 64 + fi * 16 + g * 4 + r];

    __syncthreads();

    // A fragments -> registers (held for the whole kernel)
    f16x8 a[4][4];
    #pragma unroll
    for (int fi = 0; fi < 4; ++fi) {
        const int row = wn * 64 + fi * 16 + r16;
        const int sw = (g ^ ((row >> 1) & 3)) << 3;
        #pragma unroll
        for (int k = 0; k < 4; ++k)
            a[fi][k] = *(const f16x8*)&smem[k * 4096 + row * 32 + sw];
    }

    f32x4 acc[4][4];
    #pragma unroll
    for (int fi = 0; fi < 4; ++fi)
        #pragma unroll
        for (int fj = 0; fj < 4; ++fj)
            acc[fi][fj] = (f32x4){0.f, 0.f, 0.f, 0.f};

    float runmin[4][4];
    int   runidx[4][4];
    #pragma unroll
    for (int fi = 0; fi < 4; ++fi)
        #pragma unroll
        for (int r = 0; r < 4; ++r) { runmin[fi][r] = 3.4e38f; runidx[fi][r] = 0; }

    for (int t = 0; t < 8; ++t) {
        const int mt = mbase + t * 128;
        stageB(GBh, sB1, mt, 1, srow, se8);           // k-half 1 of tile t
        computeB<0>(sB0, a, acc, wm, g, r16);
        __syncthreads();
        if (t < 7) stageB(GBh, sB0, mt + 128, 0, srow, se8);  // k-half 0 of t+1
        float ys[4];
        #pragma unroll
        for (int fj = 0; fj < 4; ++fj)
            ys[fj] = y2[mt + wm * 64 + fj * 16 + r16];
        computeB<1>(sB1, a, acc, wm, g, r16);

        // fold tile t into runmin/runidx, reset acc (covers stage latency)
        const int mwave = mt + wm * 64 + r16;
        #pragma unroll
        for (int fi = 0; fi < 4; ++fi) {
            #pragma unroll
            for (int r = 0; r < 4; ++r) {
                float d0 = fmaxf(fmaf(-2.f, acc[fi][0][r], xs[fi][r] + ys[0]), EPSF);
                float d1 = fmaxf(fmaf(-2.f, acc[fi][1][r], xs[fi][r] + ys[1]), EPSF);
                float d2v = fmaxf(fmaf(-2.f, acc[fi][2][r], xs[fi][r] + ys[2]), EPSF);
                float d3 = fmaxf(fmaf(-2.f, acc[fi][3][r], xs[fi][r] + ys[3]), EPSF);
                float m01 = fminf(d0, d1);  int i01 = d1 < d0 ? 1 : 0;
                float m23 = fminf(d2v, d3); int i23 = d3 < d2v ? 3 : 2;
                float tm  = fminf(m01, m23); int ti = m23 < m01 ? i23 : i01;
                if (tm < runmin[fi][r]) {
                    runmin[fi][r] = tm;
                    runidx[fi][r] = mwave + ti * 16;
                }
            }
            #pragma unroll
            for (int fj = 0; fj < 4; ++fj)
                acc[fi][fj] = (f32x4){0.f, 0.f, 0.f, 0.f};
        }
        __syncthreads();
    }

    // ---- final: pack, 16-lane reduce, atomicMin ----
    #pragma unroll
    for (int fi = 0; fi < 4; ++fi) {
        #pragma unroll
        for (int r = 0; r < 4; ++r) {
            const int n = n0 + wn * 64 + fi * 16 + g * 4 + r;
            u64 best = ((u64)__float_as_uint(runmin[fi][r]) << 32)
                     | (unsigned)runidx[fi][r];
            #pragma unroll
            for (int off = 1; off < 16; off <<= 1)
                best = umin64(best, (u64)__shfl_xor((unsigned long long)best, off));
            if (r16 == 0) atomicMin(&packed[n], best);
        }
    }
}

// ------- Phase C1: per-batch argmax of patch score + EXACT fp32 rescore -----
__global__ __launch_bounds__(256) void argmax_kernel(
        const u64* __restrict__ packed,
        const float* __restrict__ emb, const float* __restrict__ bank,
        const float* __restrict__ x2, const float* __restrict__ y2,
        uint4* __restrict__ binfo) {
    const int b = blockIdx.x, tid = threadIdx.x;
    __shared__ u64 red[256];
    __shared__ float fred[256];
    __shared__ unsigned s_p, s_nn;
    u64 bk = 0;
    for (int p = tid; p < PPB; p += 256) {
        u64 pk = packed[(size_t)b * PPB + p];
        unsigned d2b = (unsigned)(pk >> 32);
        u64 key = ((u64)d2b << 32) | (u64)(0xFFFFFFFFu - (unsigned)p);
        bk = umax64(bk, key);
    }
    red[tid] = bk; __syncthreads();
    for (int s = 128; s; s >>= 1) {
        if (tid < s) red[tid] = umax64(red[tid], red[tid + s]);
        __syncthreads();
    }
    if (tid == 0) {
        u64 w = red[0];
        unsigned p = 0xFFFFFFFFu - (unsigned)w;
        s_p = p;
        s_nn = (unsigned)packed[(size_t)b * PPB + p];
    }
    __syncthreads();
    const unsigned p = s_p, nn = s_nn;
    float prod = 0.f;
    if (tid < DIMD)
        prod = emb[(size_t)(b * PPB + p) * DIMD + tid] * bank[(size_t)nn * DIMD + tid];
    fred[tid] = prod; __syncthreads();
    for (int s = 128; s; s >>= 1) {
        if (tid < s) fred[tid] += fred[tid + s];
        __syncthreads();
    }
    if (tid == 0) {
        float d2 = x2[b * PPB + p] + y2[nn] - 2.0f * fred[0];
        binfo[b] = make_uint4(p, nn, __float_as_uint(fmaxf(d2, EPSF)), 0u);
    }
}

// --------- Phase C2: approx dist^2(nn_sample, bank) from fp16 GB -----------
// Selection-only (final distances are exactly rescored in final_kernel).
// GB rows are quarter-swizzled per row; XOR-align chunks: delta from nn^m.
__global__ __launch_bounds__(256) void dnn_kernel(
        const _Float16* __restrict__ GBh,
        const float* __restrict__ y2,
        const uint4* __restrict__ binfo,
        float* __restrict__ dnn) {
    const int b = blockIdx.y;
    const unsigned nn = binfo[b].y;
    __shared__ _Float16 nv[DIMD];      // stored-order chunks of row nn
    if (threadIdx.x < DIMD) nv[threadIdx.x] = GBh[(size_t)nn * DIMD + threadIdx.x];
    __syncthreads();
    const int m = blockIdx.x * 256 + threadIdx.x;
    const int delta = (((nn >> 1) ^ (m >> 1)) & 3);
    const _Float16* row = GBh + (size_t)m * DIMD;
    float dot = 0.f;
    #pragma unroll
    for (int q = 0; q < 4; ++q)
        #pragma unroll
        for (int jj2 = 0; jj2 < 4; ++jj2) {
            f16x8 ym = *(const f16x8*)(row + q * 32 + jj2 * 8);
            f16x8 xm = *(const f16x8*)&nv[q * 32 + (jj2 ^ delta) * 8];
            #pragma unroll
            for (int e = 0; e < 8; ++e)
                dot += (float)ym[e] * (float)xm[e];
        }
    float d2 = y2[nn] + y2[m] - 2.0f * dot;
    dnn[(size_t)b * M_BANK + m] = fmaxf(d2, EPSF);
}

// ---------------- Phase C3: top-9 (reg lists + merge), softmax, output -----
__global__ __launch_bounds__(256) void final_kernel(
        const float* __restrict__ emb,
        const float* __restrict__ bank,
        const float* __restrict__ x2,
        const float* __restrict__ y2,
        const uint4* __restrict__ binfo,
        const float* __restrict__ dnn,
        float* __restrict__ out) {
    const int b = blockIdx.x, tid = threadIdx.x;
    __shared__ u64 lists[256 * KNN];   // 18 KiB
    __shared__ u64 red4[4];
    __shared__ u64 s_wkey;
    __shared__ unsigned s_sel[KNN];
    __shared__ float s_dist[KNN];
    __shared__ float xv[DIMD];

    const uint4 info = binfo[b];
    const unsigned nstar = info.x;
    const float d2star = __uint_as_float(info.z);
    if (tid < DIMD) xv[tid] = emb[(size_t)(b * PPB + nstar) * DIMD + tid];

    u64 lst[KNN];
    #pragma unroll
    for (int s = 0; s < KNN; ++s) lst[s] = ~0ull;
    for (int i = 0; i < M_BANK / 256; ++i) {
        const int m = tid + (i << 8);
        const float v = dnn[(size_t)b * M_BANK + m];
        const u64 key = ((u64)__float_as_uint(v) << 32) | (unsigned)m;
        if (key < lst[KNN - 1]) {
            lst[KNN - 1] = key;
            #pragma unroll
            for (int s = KNN - 1; s > 0; --s) {
                u64 a = lst[s - 1], cc = lst[s];
                lst[s - 1] = umin64(a, cc);
                lst[s]     = umax64(a, cc);
            }
        }
    }
    #pragma unroll
    for (int s = 0; s < KNN; ++s) lists[tid * KNN + s] = lst[s];
    __syncthreads();

    int p = 0;
    for (int r = 0; r < KNN; ++r) {
        u64 h = (p < KNN) ? lists[tid * KNN + p] : ~0ull;
        #pragma unroll
        for (int off = 1; off < 64; off <<= 1)
            h = umin64(h, (u64)__shfl_xor((unsigned long long)h, off));
        if ((tid & 63) == 0) red4[tid >> 6] = h;
        __syncthreads();
        if (tid == 0) {
            u64 w = umin64(umin64(red4[0], red4[1]), umin64(red4[2], red4[3]));
            s_wkey = w;
            s_sel[r] = (unsigned)w;
        }
        __syncthreads();
        const u64 w = s_wkey;
        if (p < KNN && lists[tid * KNN + p] == w) ++p;
    }

    // exact fp32 distances for the 9 selected (order of 1..8 irrelevant:
    // output uses element 0 (self-match) + order-invariant sum)
    if (tid < KNN) {
        const unsigned s = s_sel[tid];
        const float* srow = bank + (size_t)s * DIMD;
        float dot = 0.f;
        for (int d = 0; d < DIMD; ++d) dot += srow[d] * xv[d];
        float d2 = x2[b * PPB + nstar] + y2[s] - 2.0f * dot;
        s_dist[tid] = sqrtf(fmaxf(d2, EPSF));
    }
    __syncthreads();

    if (tid == 0) {
        float mx = s_dist[0];
        for (int i = 1; i < KNN; ++i) mx = fmaxf(mx, s_dist[i]);
        float sum = 0.f, e0 = 0.f;
        for (int i = 0; i < KNN; ++i) {
            float e = expf(s_dist[i] - mx);
            sum += e;
            if (i == 0) e0 = e;
        }
        float w = 1.0f - e0 / sum;
        out[b] = w * sqrtf(fmaxf(d2star, EPSF));
    }
}

extern "C" void kernel_launch(void* const* d_in, const int* in_sizes, int n_in,
                              void* d_out, int out_size, void* d_ws, size_t ws_size,
                              hipStream_t stream) {
    const float* emb  = (const float*)d_in[0];
    const float* bank = (const float*)d_in[1];
    float* out = (float*)d_out;

    char* ws = (char*)d_ws;
    u64*      packed = (u64*)      (ws + 0);         //  50176 B
    float*    x2     = (float*)    (ws + 65536);     //  25088 B
    float*    y2     = (float*)    (ws + 131072);    //  65536 B
    uint4*    binfo  = (uint4*)    (ws + 200704);    //    128 B
    float*    dnn    = (float*)    (ws + 262144);    // 524288 B
    _Float16* GAh    = (_Float16*) (ws + 786432);    // 1605632 B
    _Float16* GBh    = (_Float16*) (ws + 2392064);   // 4194304 B  (end 6586368)

    {
        const int rows = M_BANK + N_EMB;             // 22656
        const int blocks = rows * 16 / 256;          // 1416
        convert_kernel<<<blocks, 256, 0, stream>>>(emb, bank, GAh, GBh, x2, y2, packed);
    }

    dist_min_mfma<<<49 * 16, 256, 0, stream>>>(GAh, GBh, x2, y2, packed);

    argmax_kernel<<<BATCH, 256, 0, stream>>>(packed, emb, bank, x2, y2, binfo);

    dnn_kernel<<<dim3(M_BANK / 256, BATCH), 256, 0, stream>>>(GBh, y2, binfo, dnn);

    final_kernel<<<BATCH, 256, 0, stream>>>(emb, bank, x2, y2, binfo, dnn, out);
}